// Round 1
// baseline (392.278 us; speedup 1.0000x reference)
//
#include <hip/hip_runtime.h>
#include <stdint.h>

#define T_TOK 1024
#define H_DIM 1024
#define I_DIM 2816
#define E_NUM 8

typedef __attribute__((ext_vector_type(8))) short bf16x8;
typedef __attribute__((ext_vector_type(4))) float f32x4;

struct Meta { int counts[E_NUM]; int tiles[E_NUM]; int offs[E_NUM]; };

__device__ __forceinline__ unsigned short f2b(float f) {
    unsigned u = __float_as_uint(f);
    u += 0x7fffu + ((u >> 16) & 1u);   // round-to-nearest-even
    return (unsigned short)(u >> 16);
}

// ---------------- routing: softmax -> top2 -> renorm -> grouped token lists ----------------
__global__ void route_kernel(const float* __restrict__ logits,
                             int* __restrict__ tok, float* __restrict__ gate,
                             Meta* __restrict__ meta) {
    __shared__ int cnt[E_NUM];
    const int tid = threadIdx.x;   // == token id, blockDim=1024
    if (tid < E_NUM) cnt[tid] = 0;
    for (int j = tid; j < E_NUM * T_TOK; j += 1024) { tok[j] = 0; gate[j] = 0.f; }
    __syncthreads();

    float p[E_NUM];
    const float* lrow = logits + tid * E_NUM;
    float m = -1e30f;
    #pragma unroll
    for (int e = 0; e < E_NUM; ++e) { p[e] = lrow[e]; m = fmaxf(m, p[e]); }
    #pragma unroll
    for (int e = 0; e < E_NUM; ++e) p[e] = __expf(p[e] - m);
    int e0 = 0; float v0 = p[0];
    #pragma unroll
    for (int e = 1; e < E_NUM; ++e) if (p[e] > v0) { v0 = p[e]; e0 = e; }
    int e1 = -1; float v1 = -1.f;
    #pragma unroll
    for (int e = 0; e < E_NUM; ++e) if (e != e0 && p[e] > v1) { v1 = p[e]; e1 = e; }
    const float inv = 1.f / (v0 + v1);       // softmax denom cancels in ratio
    const float g0 = v0 * inv, g1 = v1 * inv;

    const int p0 = atomicAdd(&cnt[e0], 1);
    const int p1 = atomicAdd(&cnt[e1], 1);
    tok[e0 * T_TOK + p0] = tid; gate[e0 * T_TOK + p0] = g0;
    tok[e1 * T_TOK + p1] = tid; gate[e1 * T_TOK + p1] = g1;
    __syncthreads();
    if (tid == 0) {
        int off = 0;
        for (int e = 0; e < E_NUM; ++e) {
            const int c = cnt[e];
            const int t = (c + 127) >> 7;
            meta->counts[e] = c; meta->tiles[e] = t; meta->offs[e] = off;
            off += t * 128;
        }
    }
}

// ---------------- x fp32 -> bf16 ----------------
__global__ void cvt_x_kernel(const float* __restrict__ x, unsigned short* __restrict__ xb) {
    const int i = blockIdx.x * blockDim.x + threadIdx.x;   // 262144 threads, 4 elems each
    const float4 v = ((const float4*)x)[i];
    ushort4 o; o.x = f2b(v.x); o.y = f2b(v.y); o.z = f2b(v.z); o.w = f2b(v.w);
    ((ushort4*)xb)[i] = o;
}

// ---------------- GEMM1: act = silu(x@w1^T) * (x@w3^T), grouped per expert ----------------
// grid: (I/64, E, maxMTiles), block 256. Tile: 128 tokens x 64 I-cols (dual w1/w3), BK=32.
__launch_bounds__(256)
__global__ void gemm1_kernel(const unsigned short* __restrict__ xb,
                             const float* __restrict__ w1,
                             const float* __restrict__ w3,
                             const int* __restrict__ tok,
                             const Meta* __restrict__ meta,
                             unsigned short* __restrict__ act) {
    const int e = blockIdx.y;
    const int mt = blockIdx.z;
    if (mt >= meta->tiles[e]) return;
    const int it = blockIdx.x;
    const int tid = threadIdx.x;

    __shared__ __align__(16) unsigned short As[128 * 32];
    __shared__ __align__(16) unsigned short B1s[64 * 32];
    __shared__ __align__(16) unsigned short B3s[64 * 32];

    // A staging: 128 rows x 32 k (bf16), 512 chunks of 8 -> 2/thread
    const int arow = tid >> 2, asub = tid & 3;
    const int t0 = tok[e * T_TOK + mt * 128 + arow];
    const int t1 = tok[e * T_TOK + mt * 128 + 64 + arow];
    const unsigned short* ap0 = xb + (size_t)t0 * H_DIM + asub * 8;
    const unsigned short* ap1 = xb + (size_t)t1 * H_DIM + asub * 8;
    unsigned short* al0 = &As[arow * 32 + asub * 8];
    unsigned short* al1 = &As[(64 + arow) * 32 + asub * 8];

    // B staging: 64 rows x 32 k fp32 per matrix, 512 float4 -> 2/thread/matrix
    const int brow = tid >> 3, bsub = tid & 7;
    const size_t wbase = (size_t)e * I_DIM * H_DIM + (size_t)(it * 64) * H_DIM;
    const float* b1p0 = w1 + wbase + (size_t)brow * H_DIM + bsub * 4;
    const float* b1p1 = w1 + wbase + (size_t)(32 + brow) * H_DIM + bsub * 4;
    const float* b3p0 = w3 + wbase + (size_t)brow * H_DIM + bsub * 4;
    const float* b3p1 = w3 + wbase + (size_t)(32 + brow) * H_DIM + bsub * 4;
    unsigned short* bl10 = &B1s[brow * 32 + bsub * 4];
    unsigned short* bl11 = &B1s[(32 + brow) * 32 + bsub * 4];
    unsigned short* bl30 = &B3s[brow * 32 + bsub * 4];
    unsigned short* bl31 = &B3s[(32 + brow) * 32 + bsub * 4];

    const int wave = tid >> 6, lane = tid & 63;
    const int quad = lane >> 4, l15 = lane & 15;
    const int mbase = (wave >> 1) * 64;   // wave quadrant: 64 rows x 32 cols (dual)
    const int nbase = (wave & 1) * 32;

    f32x4 acc1[4][2], acc3[4][2];
    #pragma unroll
    for (int mi = 0; mi < 4; ++mi)
        #pragma unroll
        for (int ni = 0; ni < 2; ++ni) {
            acc1[mi][ni] = (f32x4){0.f, 0.f, 0.f, 0.f};
            acc3[mi][ni] = (f32x4){0.f, 0.f, 0.f, 0.f};
        }

    // register-double-buffered staging
    uint4 ra0 = *(const uint4*)(ap0), ra1 = *(const uint4*)(ap1);
    float4 r10 = *(const float4*)(b1p0), r11 = *(const float4*)(b1p1);
    float4 r30 = *(const float4*)(b3p0), r31 = *(const float4*)(b3p1);

    const int NK = H_DIM / 32;
    for (int ks = 0; ks < NK; ++ks) {
        __syncthreads();
        *(uint4*)al0 = ra0;
        *(uint4*)al1 = ra1;
        ushort4 c;
        c.x = f2b(r10.x); c.y = f2b(r10.y); c.z = f2b(r10.z); c.w = f2b(r10.w); *(ushort4*)bl10 = c;
        c.x = f2b(r11.x); c.y = f2b(r11.y); c.z = f2b(r11.z); c.w = f2b(r11.w); *(ushort4*)bl11 = c;
        c.x = f2b(r30.x); c.y = f2b(r30.y); c.z = f2b(r30.z); c.w = f2b(r30.w); *(ushort4*)bl30 = c;
        c.x = f2b(r31.x); c.y = f2b(r31.y); c.z = f2b(r31.z); c.w = f2b(r31.w); *(ushort4*)bl31 = c;
        __syncthreads();
        if (ks + 1 < NK) {
            const int k0 = (ks + 1) * 32;
            ra0 = *(const uint4*)(ap0 + k0);  ra1 = *(const uint4*)(ap1 + k0);
            r10 = *(const float4*)(b1p0 + k0); r11 = *(const float4*)(b1p1 + k0);
            r30 = *(const float4*)(b3p0 + k0); r31 = *(const float4*)(b3p1 + k0);
        }
        bf16x8 a[4];
        #pragma unroll
        for (int mi = 0; mi < 4; ++mi)
            a[mi] = *(const bf16x8*)&As[(mbase + mi * 16 + l15) * 32 + quad * 8];
        bf16x8 b1f[2], b3f[2];
        #pragma unroll
        for (int ni = 0; ni < 2; ++ni) {
            b1f[ni] = *(const bf16x8*)&B1s[(nbase + ni * 16 + l15) * 32 + quad * 8];
            b3f[ni] = *(const bf16x8*)&B3s[(nbase + ni * 16 + l15) * 32 + quad * 8];
        }
        #pragma unroll
        for (int mi = 0; mi < 4; ++mi)
            #pragma unroll
            for (int ni = 0; ni < 2; ++ni) {
                acc1[mi][ni] = __builtin_amdgcn_mfma_f32_16x16x32_bf16(a[mi], b1f[ni], acc1[mi][ni], 0, 0, 0);
                acc3[mi][ni] = __builtin_amdgcn_mfma_f32_16x16x32_bf16(a[mi], b3f[ni], acc3[mi][ni], 0, 0, 0);
            }
    }

    // epilogue: silu(h1)*h3 -> act (bf16). C/D layout: row=quad*4+reg, col=lane&15 (m89-verified)
    const int opad = meta->offs[e];
    #pragma unroll
    for (int mi = 0; mi < 4; ++mi)
        #pragma unroll
        for (int ni = 0; ni < 2; ++ni)
            #pragma unroll
            for (int rr = 0; rr < 4; ++rr) {
                const float v1 = acc1[mi][ni][rr];
                const float v3 = acc3[mi][ni][rr];
                const float s = v1 / (1.f + __expf(-v1)) * v3;
                const int row = opad + mt * 128 + mbase + mi * 16 + quad * 4 + rr;
                const int col = it * 64 + nbase + ni * 16 + l15;
                act[(size_t)row * I_DIM + col] = f2b(s);
            }
}

// ---------------- GEMM2: y = act @ w2^T, gate-scaled atomic scatter ----------------
// grid: (H/64, E, maxMTiles), block 256. Tile: 128 rows x 64 H-cols, BK=32, K=2816.
__launch_bounds__(256)
__global__ void gemm2_kernel(const unsigned short* __restrict__ act,
                             const float* __restrict__ w2,
                             const int* __restrict__ tok,
                             const float* __restrict__ gate,
                             const Meta* __restrict__ meta,
                             float* __restrict__ out) {
    const int e = blockIdx.y;
    const int mt = blockIdx.z;
    if (mt >= meta->tiles[e]) return;
    const int it = blockIdx.x;
    const int tid = threadIdx.x;
    const int opad = meta->offs[e];

    __shared__ __align__(16) unsigned short As[128 * 32];
    __shared__ __align__(16) unsigned short Bs[64 * 32];

    const int arow = tid >> 2, asub = tid & 3;
    const unsigned short* ap0 = act + (size_t)(opad + mt * 128 + arow) * I_DIM + asub * 8;
    const unsigned short* ap1 = act + (size_t)(opad + mt * 128 + 64 + arow) * I_DIM + asub * 8;
    unsigned short* al0 = &As[arow * 32 + asub * 8];
    unsigned short* al1 = &As[(64 + arow) * 32 + asub * 8];

    const int brow = tid >> 3, bsub = tid & 7;
    const size_t wbase = (size_t)e * H_DIM * I_DIM + (size_t)(it * 64) * I_DIM;
    const float* bp0 = w2 + wbase + (size_t)brow * I_DIM + bsub * 4;
    const float* bp1 = w2 + wbase + (size_t)(32 + brow) * I_DIM + bsub * 4;
    unsigned short* bl0 = &Bs[brow * 32 + bsub * 4];
    unsigned short* bl1 = &Bs[(32 + brow) * 32 + bsub * 4];

    const int wave = tid >> 6, lane = tid & 63;
    const int quad = lane >> 4, l15 = lane & 15;
    const int mbase = (wave >> 1) * 64;
    const int nbase = (wave & 1) * 32;

    f32x4 acc[4][2];
    #pragma unroll
    for (int mi = 0; mi < 4; ++mi)
        #pragma unroll
        for (int ni = 0; ni < 2; ++ni) acc[mi][ni] = (f32x4){0.f, 0.f, 0.f, 0.f};

    uint4 ra0 = *(const uint4*)(ap0), ra1 = *(const uint4*)(ap1);
    float4 rb0 = *(const float4*)(bp0), rb1 = *(const float4*)(bp1);

    const int NK = I_DIM / 32;   // 88
    for (int ks = 0; ks < NK; ++ks) {
        __syncthreads();
        *(uint4*)al0 = ra0;
        *(uint4*)al1 = ra1;
        ushort4 c;
        c.x = f2b(rb0.x); c.y = f2b(rb0.y); c.z = f2b(rb0.z); c.w = f2b(rb0.w); *(ushort4*)bl0 = c;
        c.x = f2b(rb1.x); c.y = f2b(rb1.y); c.z = f2b(rb1.z); c.w = f2b(rb1.w); *(ushort4*)bl1 = c;
        __syncthreads();
        if (ks + 1 < NK) {
            const int k0 = (ks + 1) * 32;
            ra0 = *(const uint4*)(ap0 + k0); ra1 = *(const uint4*)(ap1 + k0);
            rb0 = *(const float4*)(bp0 + k0); rb1 = *(const float4*)(bp1 + k0);
        }
        bf16x8 a[4];
        #pragma unroll
        for (int mi = 0; mi < 4; ++mi)
            a[mi] = *(const bf16x8*)&As[(mbase + mi * 16 + l15) * 32 + quad * 8];
        bf16x8 bf[2];
        #pragma unroll
        for (int ni = 0; ni < 2; ++ni)
            bf[ni] = *(const bf16x8*)&Bs[(nbase + ni * 16 + l15) * 32 + quad * 8];
        #pragma unroll
        for (int mi = 0; mi < 4; ++mi)
            #pragma unroll
            for (int ni = 0; ni < 2; ++ni)
                acc[mi][ni] = __builtin_amdgcn_mfma_f32_16x16x32_bf16(a[mi], bf[ni], acc[mi][ni], 0, 0, 0);
    }

    // epilogue: out[token][col] += gate * y  (padded rows have gate=0, token=0 -> add 0)
    #pragma unroll
    for (int mi = 0; mi < 4; ++mi)
        #pragma unroll
        for (int rr = 0; rr < 4; ++rr) {
            const int r = mt * 128 + mbase + mi * 16 + quad * 4 + rr;
            const int t = tok[e * T_TOK + r];
            const float g = gate[e * T_TOK + r];
            #pragma unroll
            for (int ni = 0; ni < 2; ++ni) {
                const int col = it * 64 + nbase + ni * 16 + l15;
                atomicAdd(&out[(size_t)t * H_DIM + col], g * acc[mi][ni][rr]);
            }
        }
}

extern "C" void kernel_launch(void* const* d_in, const int* in_sizes, int n_in,
                              void* d_out, int out_size, void* d_ws, size_t ws_size,
                              hipStream_t stream) {
    const float* x      = (const float*)d_in[0];
    const float* logits = (const float*)d_in[1];
    const float* w1     = (const float*)d_in[2];
    const float* w3     = (const float*)d_in[3];
    const float* w2     = (const float*)d_in[4];
    float* out = (float*)d_out;

    char* ws = (char*)d_ws;
    int*   tok  = (int*)ws;                                   // 8*1024 ints   (32 KB)
    float* gate = (float*)(ws + 32768);                       // 8*1024 floats (32 KB)
    Meta*  meta = (Meta*)(ws + 65536);
    unsigned short* xb  = (unsigned short*)(ws + 131072);     // 1M bf16 (2 MB)
    unsigned short* act = (unsigned short*)(ws + 131072 + 2097152); // <=3072 x 2816 bf16 (~16.5 MB)

    hipMemsetAsync(d_out, 0, (size_t)T_TOK * H_DIM * sizeof(float), stream);
    route_kernel<<<1, 1024, 0, stream>>>(logits, tok, gate, meta);
    cvt_x_kernel<<<T_TOK * H_DIM / 4 / 256, 256, 0, stream>>>(x, xb);
    gemm1_kernel<<<dim3(I_DIM / 64, E_NUM, 8), 256, 0, stream>>>(xb, w1, w3, tok, meta, act);
    gemm2_kernel<<<dim3(H_DIM / 64, E_NUM, 8), 256, 0, stream>>>(act, w2, tok, gate, meta, out);
}